// Round 7
// baseline (438.664 us; speedup 1.0000x reference)
//
#include <hip/hip_runtime.h>
#include <math.h>

typedef __bf16 bf16_t;
typedef unsigned char u8;
typedef long i64;
typedef __attribute__((ext_vector_type(8))) __bf16 bf16x8;
typedef __attribute__((ext_vector_type(4))) __bf16 bf16x4;
typedef __attribute__((ext_vector_type(4))) float f32x4;
typedef __attribute__((ext_vector_type(4))) int i32x4;
typedef __attribute__((ext_vector_type(8))) int i32x8;

#define AS_GLOBAL __attribute__((address_space(1)))
#define AS_LDS    __attribute__((address_space(3)))

__device__ __forceinline__ void async_copy16(const void* g, void* l) {
  __builtin_amdgcn_global_load_lds((const AS_GLOBAL void*)g, (AS_LDS void*)l, 16, 0, 0);
}

__device__ __forceinline__ u8 to_fp8(float v) {
  return (u8)(__builtin_amdgcn_cvt_pk_fp8_f32(v, v, 0, false) & 0xff);
}

// merged cast: y<8 -> fp8 (8 elems/thread), y>=8 -> bf16 (8 elems/thread)
struct CastArgs {
  const float* s[10];
  void* d[10];
  int n[10];
};

__global__ __launch_bounds__(256) void cast_all(CastArgs a) {
  const int y = blockIdx.y;
  const float* s = a.s[y];
  const int n = a.n[y];
  int i = (blockIdx.x * 256 + threadIdx.x) * 8;
  if (i >= n) return;
  float4 v0 = *(const float4*)(s + i);
  float4 v1 = *(const float4*)(s + i + 4);
  if (y < 8) {
    u8* d = (u8*)a.d[y];
    int w0 = __builtin_amdgcn_cvt_pk_fp8_f32(v0.x, v0.y, 0, false);
    w0 = __builtin_amdgcn_cvt_pk_fp8_f32(v0.z, v0.w, w0, true);
    int w1 = __builtin_amdgcn_cvt_pk_fp8_f32(v1.x, v1.y, 0, false);
    w1 = __builtin_amdgcn_cvt_pk_fp8_f32(v1.z, v1.w, w1, true);
    int2 o; o.x = w0; o.y = w1;
    *(int2*)(d + i) = o;
  } else {
    bf16_t* d = (bf16_t*)a.d[y];
    bf16x8 o;
    o[0] = (bf16_t)v0.x; o[1] = (bf16_t)v0.y; o[2] = (bf16_t)v0.z; o[3] = (bf16_t)v0.w;
    o[4] = (bf16_t)v1.x; o[5] = (bf16_t)v1.y; o[6] = (bf16_t)v1.z; o[7] = (bf16_t)v1.w;
    *(bf16x8*)(d + i) = o;
  }
}

// XCD-contiguous bijective block remap (nwg % 8 == 0 for all our grids).
__device__ __forceinline__ void xcd_remap(int& bx, int& by, int& bz) {
  const int gx = gridDim.x, gy = gridDim.y;
  const int nwg = gx * gy * gridDim.z;
  const int cpx = nwg >> 3;
  int flat = (blockIdx.z * gy + blockIdx.y) * gx + blockIdx.x;
  int swz = (flat & 7) * cpx + (flat >> 3);
  bx = swz % gx;
  by = (swz / gx) % gy;
  bz = swz / (gx * gy);
}

// read a 32B MX A/B fragment (row rr, k-group q) from a swizzled [*][128B] tile
#define LDFRAG(dst, base, rr) do { \
    int _r = (rr); \
    i32x4 _lo = *(const i32x4*)&(base)[_r * 128 + (((2 * q)) ^ (_r & 7)) * 16]; \
    i32x4 _hi = *(const i32x4*)&(base)[_r * 128 + (((2 * q + 1)) ^ (_r & 7)) * 16]; \
    dst = __builtin_shufflevector(_lo, _hi, 0, 1, 2, 3, 4, 5, 6, 7); \
  } while (0)

#define MXMFMA(D, AF, BF) \
  D = __builtin_amdgcn_mfma_scale_f32_16x16x128_f8f6f4( \
      AF, BF, D, 0, 0, 0, 0x7F7F7F7F, 0, 0x7F7F7F7F)

// ---------------- fused attention: res = softmax(QK^T/sqrt(D)) @ V ----------
// Per block: 128 Q-rows of one (dir,head); 8 waves x 16 rows; Q in registers.
// Loop over 16 n-tiles (128 keys each): stage K-tile[128x512B] + V-tile
// [512x128B] (R5-proven single-buffer syncthreads scheme), QK (32 MFMA/wave),
// exp + per-lane rowsum accum + fp8 pack into swizzled S_lds (own-wave slice
// only -> no cross-wave barrier), PV (32 MFMA/wave) accumulates 16x512 f32.
// End: shfl-reduce rowsums, normalize in-register, write bf16 res.
// Replaces the QK + PV dispatches and the 128MB S8 HBM round-trip + partials.
__global__ __launch_bounds__(512, 2) void attn_fused(
    const u8* __restrict__ q8, const u8* __restrict__ k8, const u8* __restrict__ vt8,
    bf16_t* __restrict__ res, float scale)
{
  __shared__ __align__(16) u8 klds[65536];   // [4 ks][128 rows][128B swizzled]
  __shared__ __align__(16) u8 vlds[65536];   // [512 d-rows][128B swizzled]
  __shared__ __align__(16) u8 slds[16384];   // [128 m][128B swizzled fp8 S]

  int bx, by, bz;
  xcd_remap(bx, by, bz);     // grid (16 row-blocks, 16 z): same-z blocks share XCD

  const int tid = threadIdx.x;
  const int lane = tid & 63;
  const int wid = tid >> 6;          // 0..7, wave owns rows wid*16..wid*16+15
  const int q = lane >> 4;           // k-group
  const int r16 = lane & 15;
  const int m0 = bx * 128;
  const int dir = by >> 3, head = by & 7;

  const u8* Qp = q8 + (long)dir * 2048 * 4096 + (long)head * 512;
  const u8* Kp = k8 + (long)dir * 2048 * 4096 + (long)head * 512;
  const u8* Vp = vt8 + (long)dir * 8 * 512 * 2048 + (long)head * 512 * 2048;
  bf16_t* Cp = res + (long)dir * 2048 * 4096 + (long)head * 512;

  // staging geometry: 4096 16B segs per 64KB tile, 8/thread, XOR swizzle.
  // K/Q tile [4ks][128r][8seg]: p=j*512+tid -> ks=p>>10, row=(p>>3)&127, seg=p&7
  // V tile   [512r][8seg]:                    row=p>>3,          seg=p&7
  int ldsOff[8];
  const u8* gK[8];
  const u8* gV[8];
#pragma unroll
  for (int j = 0; j < 8; ++j) {
    int p = j * 512 + tid;
    int rowk = (p >> 3) & 127;
    int ks = j >> 1;
    int seg = p & 7;
    ldsOff[j] = p * 16;
    gK[j] = Kp + (long)rowk * 4096 + ks * 128 + ((seg ^ (rowk & 7)) * 16);
    int rowv = p >> 3;
    gV[j] = Vp + (long)rowv * 2048 + ((seg ^ (rowv & 7)) * 16);
  }

  // ---- prologue: stage Q block into klds, pull Q frags to registers ----
  const long qdelta = (Qp - Kp) + (long)m0 * 4096;
#pragma unroll
  for (int j = 0; j < 8; ++j) async_copy16(gK[j] + qdelta, &klds[ldsOff[j]]);
  __syncthreads();
  i32x8 qf[4];
#pragma unroll
  for (int ks = 0; ks < 4; ++ks) LDFRAG(qf[ks], &klds[ks * 16384], wid * 16 + r16);
  __syncthreads();   // q frags landed (lgkm drained); klds free for K tiles

  f32x4 acc[32];
#pragma unroll
  for (int dj = 0; dj < 32; ++dj) acc[dj] = f32x4{0.f, 0.f, 0.f, 0.f};
  float rs4[4] = {0.f, 0.f, 0.f, 0.f};

#pragma unroll 1
  for (int t = 0; t < 16; ++t) {
    // stage K(t) rows t*128.., V(t) cols t*128..
#pragma unroll
    for (int j = 0; j < 8; ++j) {
      async_copy16(gK[j] + (long)t * 524288, &klds[ldsOff[j]]);
      async_copy16(gV[j] + t * 128, &vlds[ldsOff[j]]);
    }
    __syncthreads();

    // QK: S-strip 16x128 per wave
    f32x4 sacc[8];
#pragma unroll
    for (int j = 0; j < 8; ++j) sacc[j] = f32x4{0.f, 0.f, 0.f, 0.f};
#pragma unroll
    for (int ks = 0; ks < 4; ++ks) {
#pragma unroll
      for (int j = 0; j < 8; ++j) {
        i32x8 bf;
        LDFRAG(bf, &klds[ks * 16384], j * 16 + r16);
        MXMFMA(sacc[j], qf[ks], bf);
      }
    }

    // exp + rowsum accum + fp8 pack into swizzled slds (own rows only)
#pragma unroll
    for (int j = 0; j < 8; ++j) {
#pragma unroll
      for (int r = 0; r < 4; ++r) {
        float pv = __expf(sacc[j][r] * scale);
        rs4[r] += pv;
        int m = q * 4 + r;   // row within wave strip; (wid*16+m)&7 == m&7
        slds[(wid * 16 + m) * 128 + ((j ^ (m & 7)) * 16) + r16] = to_fp8(pv);
      }
    }
    __syncthreads();   // S writes drained (also fences klds/vlds reads)

    // PV: acc[16x512] += S[16x128] @ V[128x512]; A-frag = own S strip
    i32x8 sa;
    LDFRAG(sa, slds, wid * 16 + r16);
#pragma unroll
    for (int dj = 0; dj < 32; ++dj) {
      i32x8 bv;
      LDFRAG(bv, vlds, dj * 16 + r16);
      MXMFMA(acc[dj], sa, bv);
    }
    __syncthreads();   // all waves done with klds/vlds before restage
  }

  // rowsum reduce over the 16-lane groups, normalize, store bf16
#pragma unroll
  for (int m = 1; m <= 8; m <<= 1)
#pragma unroll
    for (int r = 0; r < 4; ++r) rs4[r] += __shfl_xor(rs4[r], m, 64);
  float w[4];
#pragma unroll
  for (int r = 0; r < 4; ++r) w[r] = 1.f / rs4[r];

#pragma unroll
  for (int dj = 0; dj < 32; ++dj) {
    const int colg = dj * 16 + r16;
#pragma unroll
    for (int r = 0; r < 4; ++r) {
      const long row = m0 + wid * 16 + q * 4 + r;
      Cp[row * 4096 + colg] = (bf16_t)(acc[dj][r] * w[r]);
    }
  }
}

// ---------------- fp8 GEMM (proj only now): C = A @ B^T ---------------------
// 128x128 tile, BK=128, MX-scaled mfma 16x16x128 fp8 (scale=1.0),
// single-buffer __syncthreads loop (R3/R5 A/B-proven for nt=4),
// global_load_lds(16B) + XOR swizzle.
// MODE 2 (proj): A-switch at n0 (Xq for cols<4096, Xkv beyond); fp8 outputs:
//   cols [0,4096): q8;  [4096,8192): K8;  [8192,12288): V8 transposed pack.
template <int MODE>
__global__ __launch_bounds__(256, 2) void gemm_f8(
    const u8* __restrict__ A, const u8* __restrict__ A2, int lda, long aDir, long aHead,
    const u8* __restrict__ B, int ldb, long bDir, long bHead,
    void* __restrict__ Cv, int ldc, long cDir, long cHead,
    u8* __restrict__ K8, u8* __restrict__ V8,
    const float* __restrict__ bq0, const float* __restrict__ bk0, const float* __restrict__ bv0,
    const float* __restrict__ bq1, const float* __restrict__ bk1, const float* __restrict__ bv1,
    float scale, int K)
{
  __shared__ __align__(16) u8 lds_a[128 * 128];
  __shared__ __align__(16) u8 lds_b[128 * 128];

  int bx, by, bz;
  xcd_remap(bx, by, bz);

  const int tid = threadIdx.x;
  const int lane = tid & 63;
  const int wid = tid >> 6;
  const int wm = (wid >> 1) * 64;
  const int wn = (wid & 1) * 64;
  const int m0 = by * 128;
  const int n0 = bx * 128;
  const int z = bz;
  const int dir = z;

  const u8* Aq  = dir ? A : A2;    // A=img8, A2=meta8; dir0 queries=metadata
  const u8* Akv = dir ? A2 : A;
  const u8* Ap = (n0 < 4096) ? Aq : Akv;
  const u8* Bp = B + (long)dir * bDir;
  u8* C8 = (u8*)Cv + (long)dir * cDir;

  const u8* gA[4];
  const u8* gB[4];
  int ldsOff[4];
#pragma unroll
  for (int j = 0; j < 4; ++j) {
    int p = j * 256 + tid;
    int row = p >> 3;
    int ksl = (p & 7) ^ (row & 7);
    ldsOff[j] = p * 16;
    gA[j] = Ap + (long)(m0 + row) * lda + ksl * 16;
    gB[j] = Bp + (long)(n0 + row) * ldb + ksl * 16;
  }

  f32x4 acc[4][4];
#pragma unroll
  for (int i = 0; i < 4; ++i)
#pragma unroll
    for (int j = 0; j < 4; ++j) acc[i][j] = f32x4{0.f, 0.f, 0.f, 0.f};

  const int q = lane >> 4;
  const int r16 = lane & 15;

  for (int kt = 0; kt < K; kt += 128) {
#pragma unroll
    for (int j = 0; j < 4; ++j) {
      async_copy16(gA[j] + kt, &lds_a[ldsOff[j]]);
      async_copy16(gB[j] + kt, &lds_b[ldsOff[j]]);
    }
    __syncthreads();
    i32x8 af[4], bfr[4];
#pragma unroll
    for (int i = 0; i < 4; ++i) {
      LDFRAG(af[i], lds_a, wm + i * 16 + r16);
      LDFRAG(bfr[i], lds_b, wn + i * 16 + r16);
    }
#pragma unroll
    for (int i = 0; i < 4; ++i)
#pragma unroll
      for (int j = 0; j < 4; ++j)
        MXMFMA(acc[i][j], af[i], bfr[j]);
    __syncthreads();
  }

  // C/D layout: col=lane&15, row=(lane>>4)*4+reg  [m89-verified]
  const float* bq = dir ? bq1 : bq0;
  const float* bk = dir ? bk1 : bk0;
  const float* bv = dir ? bv1 : bv0;
  u8* k8p = K8 + (long)dir * 2048 * 4096;
  u8* v8p = V8 + (long)dir * 8 * 512 * 2048;
#pragma unroll
  for (int i = 0; i < 4; ++i) {
    const int row0 = m0 + wm + i * 16 + q * 4;
#pragma unroll
    for (int j = 0; j < 4; ++j) {
      const int colg = n0 + wn + j * 16 + r16;
      if (n0 < 4096) {
        float bvv = bq[colg];
#pragma unroll
        for (int r = 0; r < 4; ++r)
          C8[(long)(row0 + r) * 4096 + colg] = to_fp8(acc[i][j][r] + bvv);
      } else if (n0 < 8192) {
        int kc = colg - 4096;
        float bvv = bk[kc];
#pragma unroll
        for (int r = 0; r < 4; ++r)
          k8p[(long)(row0 + r) * 4096 + kc] = to_fp8(acc[i][j][r] + bvv);
      } else {
        int vcol = colg - 8192;
        float bvv = bv[vcol];
        int w = __builtin_amdgcn_cvt_pk_fp8_f32(acc[i][j][0] + bvv, acc[i][j][1] + bvv, 0, false);
        w = __builtin_amdgcn_cvt_pk_fp8_f32(acc[i][j][2] + bvv, acc[i][j][3] + bvv, w, true);
        *(int*)(v8p + (long)vcol * 2048 + row0) = w;   // 4 rows of V^T col
      }
    }
  }
}

// ---------------- bf16 split-K output linear, both dirs batched -------------
// z: dir=z>>2, sp=z&3. C[z] (f32) = res[dir][:, sp*Ks:] @ wl[dir][:, sp*Ks:]^T
__global__ __launch_bounds__(256, 2) void gemm_splitk(
    const bf16_t* __restrict__ A, int lda, long aDir,
    const bf16_t* __restrict__ B, int ldb, long bDir,
    float* __restrict__ C, int ldc, long zC, int Ks)
{
  __shared__ __align__(16) bf16_t lds_a[128 * 64];
  __shared__ __align__(16) bf16_t lds_b[128 * 64];

  int bx, by, bz;
  xcd_remap(bx, by, bz);

  const int tid = threadIdx.x;
  const int lane = tid & 63;
  const int wid = tid >> 6;
  const int wm = (wid >> 1) * 64;
  const int wn = (wid & 1) * 64;
  const int m0 = by * 128;
  const int n0 = bx * 128;
  const int z = bz;
  const int dir = z >> 2, sp = z & 3;
  A += (long)dir * aDir + (long)sp * Ks;
  B += (long)dir * bDir + (long)sp * Ks;
  C += (long)z * zC;

  const bf16_t* gA[4];
  const bf16_t* gB[4];
  int ldsOff[4];
#pragma unroll
  for (int j = 0; j < 4; ++j) {
    int p = j * 256 + tid;
    int row = p >> 3;
    int ksl = (p & 7) ^ (row & 7);
    ldsOff[j] = p * 8;
    gA[j] = A + (long)(m0 + row) * lda + ksl * 8;
    gB[j] = B + (long)(n0 + row) * ldb + ksl * 8;
  }

  f32x4 acc[4][4];
#pragma unroll
  for (int i = 0; i < 4; ++i)
#pragma unroll
    for (int j = 0; j < 4; ++j) acc[i][j] = f32x4{0.f, 0.f, 0.f, 0.f};

  const int q = lane >> 4;
  const int r16 = lane & 15;

  for (int kt = 0; kt < Ks; kt += 64) {
#pragma unroll
    for (int j = 0; j < 4; ++j) {
      async_copy16(gA[j] + kt, &lds_a[ldsOff[j]]);
      async_copy16(gB[j] + kt, &lds_b[ldsOff[j]]);
    }
    __syncthreads();
#pragma unroll
    for (int s = 0; s < 2; ++s) {
      bf16x8 af[4], bfr[4];
#pragma unroll
      for (int i = 0; i < 4; ++i) {
        int ra = wm + i * 16 + r16;
        int ka = ((s * 4 + q) ^ (ra & 7)) * 8;
        af[i] = *(const bf16x8*)&lds_a[ra * 64 + ka];
        int rb = wn + i * 16 + r16;
        int kb = ((s * 4 + q) ^ (rb & 7)) * 8;
        bfr[i] = *(const bf16x8*)&lds_b[rb * 64 + kb];
      }
#pragma unroll
      for (int i = 0; i < 4; ++i)
#pragma unroll
        for (int j = 0; j < 4; ++j)
          acc[i][j] = __builtin_amdgcn_mfma_f32_16x16x32_bf16(af[i], bfr[j], acc[i][j], 0, 0, 0);
    }
    __syncthreads();
  }

#pragma unroll
  for (int i = 0; i < 4; ++i) {
    const int row0 = m0 + wm + i * 16 + q * 4;
#pragma unroll
    for (int j = 0; j < 4; ++j) {
      const int colg = n0 + wn + j * 16 + r16;
#pragma unroll
      for (int r = 0; r < 4; ++r)
        C[(long)(row0 + r) * ldc + colg] = acc[i][j][r];
    }
  }
}

// out[row][dir*512+col] = sum_s spart[dir][s][row][col] + bias[col] + resid[row][col]
__global__ __launch_bounds__(256) void reduce_splitk(
    const float* __restrict__ spart,
    const float* __restrict__ b0, const float* __restrict__ b1,
    const float* __restrict__ r0, const float* __restrict__ r1,
    float* __restrict__ out) {
  const int dir = blockIdx.y;
  const float* part = spart + (long)dir * 4 * 2048 * 512;
  const float* bias = dir ? b1 : b0;
  const float* resid = dir ? r1 : r0;
  int i = blockIdx.x * 256 + threadIdx.x;
  int row = i >> 7;
  int col = (i & 127) * 4;
  float4 a = *(const float4*)(resid + (long)row * 512 + col);
  float4 b = *(const float4*)(bias + col);
  a.x += b.x; a.y += b.y; a.z += b.z; a.w += b.w;
  for (int s = 0; s < 4; ++s) {
    float4 p = *(const float4*)(part + (long)s * 2048 * 512 + (long)row * 512 + col);
    a.x += p.x; a.y += p.y; a.z += p.z; a.w += p.w;
  }
  *(float4*)(out + (long)row * 1024 + dir * 512 + col) = a;
}

extern "C" void kernel_launch(void* const* d_in, const int* in_sizes, int n_in,
                              void* d_out, int out_size, void* d_ws, size_t ws_size,
                              hipStream_t stream)
{
  (void)in_sizes; (void)n_in; (void)out_size; (void)ws_size;
  const int N = 2048, D = 512, HD = 4096;
  const int NW = HD * D;                       // 2,097,152

  const float* img_f  = (const float*)d_in[0];
  const float* meta_f = (const float*)d_in[1];
  float* out = (float*)d_out;

  char* pp = (char*)d_ws;
  u8*     img8  = (u8*)pp;     pp += (size_t)N * D;            // 1 MB
  u8*     meta8 = (u8*)pp;     pp += (size_t)N * D;
  u8*     w8    = (u8*)pp;     pp += (size_t)2 * 3 * NW;       // 12 MB [dir][q,k,v]
  bf16_t* wl16  = (bf16_t*)pp; pp += (size_t)2 * NW * 2;       // 8 MB
  u8*     q8    = (u8*)pp;     pp += (size_t)2 * N * HD;       // 16 MB
  u8*     k8    = (u8*)pp;     pp += (size_t)2 * N * HD;       // 16 MB
  u8*     vt8   = (u8*)pp;     pp += (size_t)2 * N * HD;       // 16 MB [dir][8][512][2048]
  bf16_t* res   = (bf16_t*)pp; pp += (size_t)2 * N * HD * 2;   // 32 MB
  float*  spart = (float*)pp;  pp += (size_t)2 * 4 * N * D * 4; // 34 MB

  const float rs = 1.f / sqrtf((float)D);
  dim3 blk(256);

  // cast X + the 6 QKV weights to fp8, output-linear weights to bf16 (1 dispatch)
  CastArgs ca;
  ca.s[0] = img_f;                    ca.d[0] = img8;          ca.n[0] = N * D;
  ca.s[1] = meta_f;                   ca.d[1] = meta8;         ca.n[1] = N * D;
  ca.s[2] = (const float*)d_in[2];    ca.d[2] = w8;            ca.n[2] = NW;
  ca.s[3] = (const float*)d_in[4];    ca.d[3] = w8 + (size_t)NW;     ca.n[3] = NW;
  ca.s[4] = (const float*)d_in[6];    ca.d[4] = w8 + (size_t)2 * NW; ca.n[4] = NW;
  ca.s[5] = (const float*)d_in[8];    ca.d[5] = w8 + (size_t)3 * NW; ca.n[5] = NW;
  ca.s[6] = (const float*)d_in[10];   ca.d[6] = w8 + (size_t)4 * NW; ca.n[6] = NW;
  ca.s[7] = (const float*)d_in[12];   ca.d[7] = w8 + (size_t)5 * NW; ca.n[7] = NW;
  ca.s[8] = (const float*)d_in[14];   ca.d[8] = wl16;          ca.n[8] = NW;
  ca.s[9] = (const float*)d_in[16];   ca.d[9] = wl16 + NW;     ca.n[9] = NW;
  cast_all<<<dim3(NW / 2048, 10), blk, 0, stream>>>(ca);

  // merged projections, both dirs: [Xq|Xkv] @ [Wq;Wk;Wv]^T -> q8/k8/vt8
  gemm_f8<2><<<dim3(96, 16, 2), blk, 0, stream>>>(
      img8, meta8, D, 0, 0,
      w8, D, (long)3 * NW, 0,
      q8, HD, (long)N * HD, 0,
      k8, vt8,
      (const float*)d_in[3], (const float*)d_in[5], (const float*)d_in[7],
      (const float*)d_in[9], (const float*)d_in[11], (const float*)d_in[13],
      1.f, D);

  // fused attention: res = softmax(QK^T * rs) @ V, both dirs x 8 heads
  attn_fused<<<dim3(16, 16), dim3(512), 0, stream>>>(q8, k8, vt8, res, rs);

  // output linear, split-K=4, both dirs (bf16 -> f32 partials in spart)
  gemm_splitk<<<dim3(4, 16, 8), blk, 0, stream>>>(
      res, HD, (long)N * HD,
      wl16, HD, (long)NW,
      spart, D, (long)N * D, 1024);   // Ks = 1024

  reduce_splitk<<<dim3(1024, 2), blk, 0, stream>>>(
      spart, (const float*)d_in[15], (const float*)d_in[17],
      img_f, meta_f, out);
}

// Round 9
// 327.190 us; speedup vs baseline: 1.3407x; 1.3407x over previous
//
#include <hip/hip_runtime.h>
#include <math.h>

typedef __bf16 bf16_t;
typedef unsigned char u8;
typedef long i64;
typedef __attribute__((ext_vector_type(8))) __bf16 bf16x8;
typedef __attribute__((ext_vector_type(4))) __bf16 bf16x4;
typedef __attribute__((ext_vector_type(4))) float f32x4;
typedef __attribute__((ext_vector_type(4))) int i32x4;
typedef __attribute__((ext_vector_type(8))) int i32x8;

#define AS_GLOBAL __attribute__((address_space(1)))
#define AS_LDS    __attribute__((address_space(3)))

__device__ __forceinline__ void async_copy16(const void* g, void* l) {
  __builtin_amdgcn_global_load_lds((const AS_GLOBAL void*)g, (AS_LDS void*)l, 16, 0, 0);
}

__device__ __forceinline__ u8 to_fp8(float v) {
  return (u8)(__builtin_amdgcn_cvt_pk_fp8_f32(v, v, 0, false) & 0xff);
}

// merged cast: y<8 -> fp8 (8 elems/thread), y>=8 -> bf16 (8 elems/thread)
struct CastArgs {
  const float* s[10];
  void* d[10];
  int n[10];
};

__global__ __launch_bounds__(256) void cast_all(CastArgs a) {
  const int y = blockIdx.y;
  const float* s = a.s[y];
  const int n = a.n[y];
  int i = (blockIdx.x * 256 + threadIdx.x) * 8;
  if (i >= n) return;
  float4 v0 = *(const float4*)(s + i);
  float4 v1 = *(const float4*)(s + i + 4);
  if (y < 8) {
    u8* d = (u8*)a.d[y];
    int w0 = __builtin_amdgcn_cvt_pk_fp8_f32(v0.x, v0.y, 0, false);
    w0 = __builtin_amdgcn_cvt_pk_fp8_f32(v0.z, v0.w, w0, true);
    int w1 = __builtin_amdgcn_cvt_pk_fp8_f32(v1.x, v1.y, 0, false);
    w1 = __builtin_amdgcn_cvt_pk_fp8_f32(v1.z, v1.w, w1, true);
    int2 o; o.x = w0; o.y = w1;
    *(int2*)(d + i) = o;
  } else {
    bf16_t* d = (bf16_t*)a.d[y];
    bf16x8 o;
    o[0] = (bf16_t)v0.x; o[1] = (bf16_t)v0.y; o[2] = (bf16_t)v0.z; o[3] = (bf16_t)v0.w;
    o[4] = (bf16_t)v1.x; o[5] = (bf16_t)v1.y; o[6] = (bf16_t)v1.z; o[7] = (bf16_t)v1.w;
    *(bf16x8*)(d + i) = o;
  }
}

// XCD-contiguous bijective block remap (nwg % 8 == 0 for all our grids).
__device__ __forceinline__ void xcd_remap(int& bx, int& by, int& bz) {
  const int gx = gridDim.x, gy = gridDim.y;
  const int nwg = gx * gy * gridDim.z;
  const int cpx = nwg >> 3;
  int flat = (blockIdx.z * gy + blockIdx.y) * gx + blockIdx.x;
  int swz = (flat & 7) * cpx + (flat >> 3);
  bx = swz % gx;
  by = (swz / gx) % gy;
  bz = swz / (gx * gy);
}

// ---------------- fp8 GEMM: C = A[M x K] @ B[N x K]^T, both dirs batched ----
// 128x128 tile, BK=128, MX-scaled mfma 16x16x128 fp8 (scale=1.0),
// global_load_lds(16B) + XOR swizzle.
// Schedule is MODE-split by K-depth (R3/R5 A/B-proven; R2/R4/R6/R8 structural
// variants all regressed or raced -> this configuration is the green anchor):
//   MODE 0/2 (nt=4):  single-buffer __syncthreads loop, 32 KB LDS, relies on
//                     inter-block TLP for latency hiding.
//   MODE 1   (nt=16): double-buffer + counted vmcnt(8) + raw barriers.
// z-decode: MODE 2: dir=z, head=0.  MODE 0/1: dir=z>>3, head=z&7.
// MODE 0 (QK):  S8 = fp8(exp(acc*scale)); fp32 rowsums -> partial[z][bx][2048]
// MODE 1 (PV):  bf16 C = acc / (sum_{b<16} partial[z][b][row])
// MODE 2 (proj): A-switch at n0 (Xq for cols<4096, Xkv beyond); fp8 outputs:
//   cols [0,4096):     q8 [dir][row][c]          = fp8(acc + bq[c])
//   cols [4096,8192):  K8 [dir][row][c-4096]     = fp8(acc + bk[..])
//   cols [8192,12288): V8 [dir][(c-8192)][row]   = fp8(acc + bv[..])  (V^T)
template <int MODE>
__global__ __launch_bounds__(256, 2) void gemm_f8(
    const u8* __restrict__ A, const u8* __restrict__ A2, int lda, long aDir, long aHead,
    const u8* __restrict__ B, int ldb, long bDir, long bHead,
    void* __restrict__ Cv, int ldc, long cDir, long cHead,
    u8* __restrict__ K8, u8* __restrict__ V8,
    float* __restrict__ partial,
    const float* __restrict__ bq0, const float* __restrict__ bk0, const float* __restrict__ bv0,
    const float* __restrict__ bq1, const float* __restrict__ bk1, const float* __restrict__ bv1,
    float scale, int K)
{
  constexpr int NBUF = (MODE == 1) ? 2 : 1;
  __shared__ __align__(16) u8 lds_a[NBUF][128 * 128];
  __shared__ __align__(16) u8 lds_b[NBUF][128 * 128];

  int bx, by, bz;
  xcd_remap(bx, by, bz);

  const int tid = threadIdx.x;
  const int lane = tid & 63;
  const int wid = tid >> 6;
  const int wm = (wid >> 1) * 64;
  const int wn = (wid & 1) * 64;
  const int m0 = by * 128;
  const int n0 = bx * 128;
  const int z = bz;
  const int dir = (MODE == 2) ? z : (z >> 3);
  const int head = (MODE == 2) ? 0 : (z & 7);

  const u8* Ap;
  if (MODE == 2) {
    const u8* Aq  = dir ? A : A2;    // A=img8, A2=meta8; dir0 queries=metadata
    const u8* Akv = dir ? A2 : A;
    Ap = (n0 < 4096) ? Aq : Akv;
  } else {
    Ap = A + (long)dir * aDir + (long)head * aHead;
  }
  const u8* Bp = B + (long)dir * bDir + (long)head * bHead;
  const long cOff = (long)dir * cDir + (long)head * cHead;
  u8*     C8 = (u8*)Cv + cOff;
  bf16_t* Cb = (bf16_t*)Cv + cOff;

  // 1024 16B segments per 128x128B tile; 4/thread; XOR swizzle phys=ks^(row&7)
  const u8* gA[4];
  const u8* gB[4];
  int ldsOff[4];
#pragma unroll
  for (int j = 0; j < 4; ++j) {
    int p = j * 256 + tid;
    int row = p >> 3;
    int ksl = (p & 7) ^ (row & 7);
    ldsOff[j] = p * 16;
    gA[j] = Ap + (long)(m0 + row) * lda + ksl * 16;
    gB[j] = Bp + (long)(n0 + row) * ldb + ksl * 16;
  }

  f32x4 acc[4][4];
#pragma unroll
  for (int i = 0; i < 4; ++i)
#pragma unroll
    for (int j = 0; j < 4; ++j) acc[i][j] = f32x4{0.f, 0.f, 0.f, 0.f};

  const int q = lane >> 4;     // k-group: lane holds k = q*32 .. q*32+31
  const int r16 = lane & 15;

  auto stage = [&](int buf, int ktOff) {
#pragma unroll
    for (int j = 0; j < 4; ++j) {
      async_copy16(gA[j] + ktOff, &lds_a[buf][ldsOff[j]]);
      async_copy16(gB[j] + ktOff, &lds_b[buf][ldsOff[j]]);
    }
  };

  // MX-scaled 16x16x128: A-frag = 32 contiguous K bytes at row=lane&15,
  // k0=(lane>>4)*32.  32 logical bytes = logical 16B segs {2q, 2q+1},
  // phys = seg^(row&7).
  auto compute = [&](const u8* la, const u8* lb) {
    i32x8 af[4], bfr[4];
#pragma unroll
    for (int i = 0; i < 4; ++i) {
      int ra = wm + i * 16 + r16;
      i32x4 alo = *(const i32x4*)&la[ra * 128 + ((2 * q) ^ (ra & 7)) * 16];
      i32x4 ahi = *(const i32x4*)&la[ra * 128 + ((2 * q + 1) ^ (ra & 7)) * 16];
      af[i] = __builtin_shufflevector(alo, ahi, 0, 1, 2, 3, 4, 5, 6, 7);
      int rb = wn + i * 16 + r16;
      i32x4 blo = *(const i32x4*)&lb[rb * 128 + ((2 * q) ^ (rb & 7)) * 16];
      i32x4 bhi = *(const i32x4*)&lb[rb * 128 + ((2 * q + 1) ^ (rb & 7)) * 16];
      bfr[i] = __builtin_shufflevector(blo, bhi, 0, 1, 2, 3, 4, 5, 6, 7);
    }
#pragma unroll
    for (int i = 0; i < 4; ++i)
#pragma unroll
      for (int j = 0; j < 4; ++j)
        acc[i][j] = __builtin_amdgcn_mfma_scale_f32_16x16x128_f8f6f4(
            af[i], bfr[j], acc[i][j],
            0 /*cbsz: fp8*/, 0 /*blgp: fp8*/,
            0, 0x7F7F7F7F,   /* scale_a = 2^0 */
            0, 0x7F7F7F7F);  /* scale_b = 2^0 */
  };

  if constexpr (MODE != 1) {
    // single-buffer, nt=4: rely on inter-block overlap
    for (int kt = 0; kt < K; kt += 128) {
      stage(0, kt);
      __syncthreads();
      compute(&lds_a[0][0], &lds_b[0][0]);
      __syncthreads();
    }
  } else {
    // double-buffer counted-vmcnt pipeline, nt=16
    const int nt = K >> 7;
    stage(0, 0);
    stage(1, 128);
    for (int t = 0; t < nt; ++t) {
      const int cur = t & 1;
      if (t + 1 < nt) {
        asm volatile("s_waitcnt vmcnt(8)" ::: "memory");  // tile t landed; t+1 in flight
      } else {
        asm volatile("s_waitcnt vmcnt(0)" ::: "memory");  // tail drain
      }
      __builtin_amdgcn_s_barrier();                       // publish tile t
      __builtin_amdgcn_sched_barrier(0);
      compute(&lds_a[cur][0], &lds_b[cur][0]);
      __builtin_amdgcn_sched_barrier(0);
      asm volatile("s_waitcnt lgkmcnt(0)" ::: "memory");  // my ds_reads done
      __builtin_amdgcn_s_barrier();                       // all waves done with buf
      if (t + 2 < nt) stage(cur, (t + 2) * 128);          // refill freed buffer
    }
  }

  // C/D layout: col=lane&15, row=(lane>>4)*4+reg  [m89-verified]
  if (MODE == 0) {   // QK
    float rowsum[4][4];
#pragma unroll
    for (int i = 0; i < 4; ++i)
#pragma unroll
      for (int r = 0; r < 4; ++r) rowsum[i][r] = 0.f;
#pragma unroll
    for (int i = 0; i < 4; ++i) {
      const int row0 = m0 + wm + i * 16 + q * 4;
#pragma unroll
      for (int j = 0; j < 4; ++j) {
        const int colg = n0 + wn + j * 16 + r16;
#pragma unroll
        for (int r = 0; r < 4; ++r) {
          float pv = __expf(acc[i][j][r] * scale);
          C8[(long)(row0 + r) * ldc + colg] = to_fp8(pv);
          rowsum[i][r] += pv;
        }
      }
    }
#pragma unroll
    for (int m = 1; m <= 8; m <<= 1)
#pragma unroll
      for (int i = 0; i < 4; ++i)
#pragma unroll
        for (int r = 0; r < 4; ++r)
          rowsum[i][r] += __shfl_xor(rowsum[i][r], m, 64);
    float* lsum = (float*)&lds_a[0][0];   // safe: loop-end barrier drained reads
    if (r16 == 0) {
#pragma unroll
      for (int i = 0; i < 4; ++i)
#pragma unroll
        for (int r = 0; r < 4; ++r)
          lsum[(wm + i * 16 + q * 4 + r) * 2 + (wid & 1)] = rowsum[i][r];
    }
    __syncthreads();
    if (tid < 128) {
      float s = lsum[tid * 2] + lsum[tid * 2 + 1];
      partial[((long)z * gridDim.x + bx) * 2048 + m0 + tid] = s;
    }
  } else if (MODE == 1) {   // PV: normalize by rowsum
#pragma unroll
    for (int i = 0; i < 4; ++i) {
      const int row0 = m0 + wm + i * 16 + q * 4;
      float w[4];
#pragma unroll
      for (int r = 0; r < 4; ++r) {
        const float* pp = partial + (long)z * 16 * 2048 + row0 + r;
        float s = 0.f;
#pragma unroll
        for (int b = 0; b < 16; ++b) s += pp[b * 2048];
        w[r] = 1.f / s;
      }
#pragma unroll
      for (int j = 0; j < 4; ++j) {
        const int colg = n0 + wn + j * 16 + r16;
#pragma unroll
        for (int r = 0; r < 4; ++r)
          Cb[(long)(row0 + r) * ldc + colg] = (bf16_t)(acc[i][j][r] * w[r]);
      }
    }
  } else {   // MODE 2: projection epilogue
    const float* bq = dir ? bq1 : bq0;
    const float* bk = dir ? bk1 : bk0;
    const float* bv = dir ? bv1 : bv0;
    u8* k8p = K8 + (long)dir * 2048 * 4096;
    u8* v8p = V8 + (long)dir * 8 * 512 * 2048;
#pragma unroll
    for (int i = 0; i < 4; ++i) {
      const int row0 = m0 + wm + i * 16 + q * 4;
#pragma unroll
      for (int j = 0; j < 4; ++j) {
        const int colg = n0 + wn + j * 16 + r16;
        if (n0 < 4096) {
          float bvv = bq[colg];
#pragma unroll
          for (int r = 0; r < 4; ++r)
            C8[(long)(row0 + r) * 4096 + colg] = to_fp8(acc[i][j][r] + bvv);
        } else if (n0 < 8192) {
          int kc = colg - 4096;
          float bvv = bk[kc];
#pragma unroll
          for (int r = 0; r < 4; ++r)
            k8p[(long)(row0 + r) * 4096 + kc] = to_fp8(acc[i][j][r] + bvv);
        } else {
          int vcol = colg - 8192;
          float bvv = bv[vcol];
          int w = __builtin_amdgcn_cvt_pk_fp8_f32(acc[i][j][0] + bvv, acc[i][j][1] + bvv, 0, false);
          w = __builtin_amdgcn_cvt_pk_fp8_f32(acc[i][j][2] + bvv, acc[i][j][3] + bvv, w, true);
          *(int*)(v8p + (long)vcol * 2048 + row0) = w;   // 4 rows of V^T col
        }
      }
    }
  }
}

// ---------------- bf16 split-K output linear, both dirs batched -------------
// z: dir=z>>2, sp=z&3. C[z] (bf16) = res[dir][:, sp*Ks:] @ wl[dir][:, sp*Ks:]^T
// Partials stored bf16 (R9 delta): halves spart HBM write + reduce read.
__global__ __launch_bounds__(256, 2) void gemm_splitk(
    const bf16_t* __restrict__ A, int lda, long aDir,
    const bf16_t* __restrict__ B, int ldb, long bDir,
    bf16_t* __restrict__ C, int ldc, long zC, int Ks)
{
  __shared__ __align__(16) bf16_t lds_a[128 * 64];
  __shared__ __align__(16) bf16_t lds_b[128 * 64];

  int bx, by, bz;
  xcd_remap(bx, by, bz);

  const int tid = threadIdx.x;
  const int lane = tid & 63;
  const int wid = tid >> 6;
  const int wm = (wid >> 1) * 64;
  const int wn = (wid & 1) * 64;
  const int m0 = by * 128;
  const int n0 = bx * 128;
  const int z = bz;
  const int dir = z >> 2, sp = z & 3;
  A += (long)dir * aDir + (long)sp * Ks;
  B += (long)dir * bDir + (long)sp * Ks;
  C += (long)z * zC;

  const bf16_t* gA[4];
  const bf16_t* gB[4];
  int ldsOff[4];
#pragma unroll
  for (int j = 0; j < 4; ++j) {
    int p = j * 256 + tid;
    int row = p >> 3;
    int ksl = (p & 7) ^ (row & 7);
    ldsOff[j] = p * 8;
    gA[j] = A + (long)(m0 + row) * lda + ksl * 8;
    gB[j] = B + (long)(n0 + row) * ldb + ksl * 8;
  }

  f32x4 acc[4][4];
#pragma unroll
  for (int i = 0; i < 4; ++i)
#pragma unroll
    for (int j = 0; j < 4; ++j) acc[i][j] = f32x4{0.f, 0.f, 0.f, 0.f};

  const int q = lane >> 4;
  const int r16 = lane & 15;

  for (int kt = 0; kt < Ks; kt += 64) {
#pragma unroll
    for (int j = 0; j < 4; ++j) {
      async_copy16(gA[j] + kt, &lds_a[ldsOff[j]]);
      async_copy16(gB[j] + kt, &lds_b[ldsOff[j]]);
    }
    __syncthreads();
#pragma unroll
    for (int s = 0; s < 2; ++s) {
      bf16x8 af[4], bfr[4];
#pragma unroll
      for (int i = 0; i < 4; ++i) {
        int ra = wm + i * 16 + r16;
        int ka = ((s * 4 + q) ^ (ra & 7)) * 8;
        af[i] = *(const bf16x8*)&lds_a[ra * 64 + ka];
        int rb = wn + i * 16 + r16;
        int kb = ((s * 4 + q) ^ (rb & 7)) * 8;
        bfr[i] = *(const bf16x8*)&lds_b[rb * 64 + kb];
      }
#pragma unroll
      for (int i = 0; i < 4; ++i)
#pragma unroll
        for (int j = 0; j < 4; ++j)
          acc[i][j] = __builtin_amdgcn_mfma_f32_16x16x32_bf16(af[i], bfr[j], acc[i][j], 0, 0, 0);
    }
    __syncthreads();
  }

#pragma unroll
  for (int i = 0; i < 4; ++i) {
    const int row0 = m0 + wm + i * 16 + q * 4;
#pragma unroll
    for (int j = 0; j < 4; ++j) {
      const int colg = n0 + wn + j * 16 + r16;
#pragma unroll
      for (int r = 0; r < 4; ++r)
        C[(long)(row0 + r) * ldc + colg] = (bf16_t)acc[i][j][r];
    }
  }
}

// out[row][dir*512+col] = sum_s spart[dir][s][row][col] + bias[col] + resid[row][col]
__global__ __launch_bounds__(256) void reduce_splitk(
    const bf16_t* __restrict__ spart,
    const float* __restrict__ b0, const float* __restrict__ b1,
    const float* __restrict__ r0, const float* __restrict__ r1,
    float* __restrict__ out) {
  const int dir = blockIdx.y;
  const bf16_t* part = spart + (long)dir * 4 * 2048 * 512;
  const float* bias = dir ? b1 : b0;
  const float* resid = dir ? r1 : r0;
  int i = blockIdx.x * 256 + threadIdx.x;
  int row = i >> 7;
  int col = (i & 127) * 4;
  float4 a = *(const float4*)(resid + (long)row * 512 + col);
  float4 b = *(const float4*)(bias + col);
  a.x += b.x; a.y += b.y; a.z += b.z; a.w += b.w;
#pragma unroll
  for (int s = 0; s < 4; ++s) {
    bf16x4 p = *(const bf16x4*)(part + (long)s * 2048 * 512 + (long)row * 512 + col);
    a.x += (float)p[0]; a.y += (float)p[1]; a.z += (float)p[2]; a.w += (float)p[3];
  }
  *(float4*)(out + (long)row * 1024 + dir * 512 + col) = a;
}

extern "C" void kernel_launch(void* const* d_in, const int* in_sizes, int n_in,
                              void* d_out, int out_size, void* d_ws, size_t ws_size,
                              hipStream_t stream)
{
  (void)in_sizes; (void)n_in; (void)out_size; (void)ws_size;
  const int N = 2048, D = 512, HD = 4096;
  const int NW = HD * D;                       // 2,097,152

  const float* img_f  = (const float*)d_in[0];
  const float* meta_f = (const float*)d_in[1];
  float* out = (float*)d_out;

  char* pp = (char*)d_ws;
  u8*     img8  = (u8*)pp;     pp += (size_t)N * D;            // 1 MB
  u8*     meta8 = (u8*)pp;     pp += (size_t)N * D;
  u8*     w8    = (u8*)pp;     pp += (size_t)2 * 3 * NW;       // 12 MB [dir][q,k,v]
  bf16_t* wl16  = (bf16_t*)pp; pp += (size_t)2 * NW * 2;       // 8 MB
  u8*     q8    = (u8*)pp;     pp += (size_t)2 * N * HD;       // 16 MB
  u8*     k8    = (u8*)pp;     pp += (size_t)2 * N * HD;       // 16 MB
  u8*     vt8   = (u8*)pp;     pp += (size_t)2 * N * HD;       // 16 MB [dir][8][512][2048]
  bf16_t* res   = (bf16_t*)pp; pp += (size_t)2 * N * HD * 2;   // 32 MB
  u8*     S8    = (u8*)pp;     pp += (size_t)2 * 8 * N * N;    // 64 MB [dir][8][N][N]
  float*  partial = (float*)pp; pp += (size_t)2 * 8 * 16 * 2048 * 4;  // 2 MB
  bf16_t* spart = (bf16_t*)S8;  // 4-split bf16 = 17MB < S8 size; safe: PV reads S8 before splitK writes

  const float rs = 1.f / sqrtf((float)D);
  dim3 blk(256);

  // cast X + the 6 QKV weights to fp8, output-linear weights to bf16 (1 dispatch)
  CastArgs ca;
  ca.s[0] = img_f;                    ca.d[0] = img8;          ca.n[0] = N * D;
  ca.s[1] = meta_f;                   ca.d[1] = meta8;         ca.n[1] = N * D;
  ca.s[2] = (const float*)d_in[2];    ca.d[2] = w8;            ca.n[2] = NW;
  ca.s[3] = (const float*)d_in[4];    ca.d[3] = w8 + (size_t)NW;     ca.n[3] = NW;
  ca.s[4] = (const float*)d_in[6];    ca.d[4] = w8 + (size_t)2 * NW; ca.n[4] = NW;
  ca.s[5] = (const float*)d_in[8];    ca.d[5] = w8 + (size_t)3 * NW; ca.n[5] = NW;
  ca.s[6] = (const float*)d_in[10];   ca.d[6] = w8 + (size_t)4 * NW; ca.n[6] = NW;
  ca.s[7] = (const float*)d_in[12];   ca.d[7] = w8 + (size_t)5 * NW; ca.n[7] = NW;
  ca.s[8] = (const float*)d_in[14];   ca.d[8] = wl16;          ca.n[8] = NW;
  ca.s[9] = (const float*)d_in[16];   ca.d[9] = wl16 + NW;     ca.n[9] = NW;
  cast_all<<<dim3(NW / 2048, 10), blk, 0, stream>>>(ca);

  // merged projections, both dirs: [Xq|Xkv] @ [Wq;Wk;Wv]^T -> q8/k8/vt8
  gemm_f8<2><<<dim3(96, 16, 2), blk, 0, stream>>>(
      img8, meta8, D, 0, 0,
      w8, D, (long)3 * NW, 0,
      q8, HD, (long)N * HD, 0,
      k8, vt8, nullptr,
      (const float*)d_in[3], (const float*)d_in[5], (const float*)d_in[7],
      (const float*)d_in[9], (const float*)d_in[11], (const float*)d_in[13],
      1.f, D);

  // QK, both dirs x 8 heads: S8 = fp8(exp(QK^T/sqrt(512))) + rowsum partials
  gemm_f8<0><<<dim3(16, 16, 16), blk, 0, stream>>>(
      q8, nullptr, HD, (long)N * HD, D,
      k8, HD, (long)N * HD, D,
      S8, N, (long)8 * N * N, (long)N * N,
      nullptr, nullptr, partial,
      nullptr, nullptr, nullptr, nullptr, nullptr, nullptr,
      rs, D);

  // PV: res = (S8 @ V) / rowsum
  gemm_f8<1><<<dim3(4, 16, 16), blk, 0, stream>>>(
      S8, nullptr, N, (long)8 * N * N, (long)N * N,
      vt8, N, (long)8 * D * N, (long)D * N,
      res, HD, (long)N * HD, D,
      nullptr, nullptr, partial,
      nullptr, nullptr, nullptr, nullptr, nullptr, nullptr,
      1.f, N);

  // output linear, split-K=4, both dirs (bf16 -> bf16 partials in spart)
  gemm_splitk<<<dim3(4, 16, 8), blk, 0, stream>>>(
      res, HD, (long)N * HD,
      wl16, HD, (long)NW,
      spart, D, (long)N * D, 1024);   // Ks = 1024

  reduce_splitk<<<dim3(1024, 2), blk, 0, stream>>>(
      spart, (const float*)d_in[15], (const float*)d_in[17],
      img_f, meta_f, out);
}